// Round 24
// baseline (35.446 us; speedup 1.0000x reference)
//
#include <hip/hip_runtime.h>

// PSROI pooling: fsam (N=8, C=245, H=80, W=80) f32, box (R=8192, 5) f32
// out (R, 245) f32. out[r, c] = mean over fsam[b, c, hs:he, ws:we].
//
// ARITHMETIC (frozen since R10, DO NOT TOUCH): bin = roi * fl32(1/7)
// (reciprocal multiply, 0x3E124925) and edges = SEPARATELY-rounded
// g*bin + off (asm barriers). Matches ref (absmax <= 0.016 << 0.0725).
//
// R23: in-register h-scan from DIRECT global loads. R22 was flat vs R20 ->
// scheduling wasn't the residual; the per-plane phase round trip was:
// raw->LDS (1600 b128 wr) -> bar -> h-scan rd 1600 + wr 1600 -> bar ->
// v-scan -> bar -> pool. Now the 320 h-scan owner threads gload their
// row-quarter (5xf4, stride-80B) straight into registers, scan (same f32
// values, same order -> bit-identical), and ds_write only the SCANNED
// rows: -3200 f4 LDS ops/plane, 2 barriers/plane instead of 3, shorter
// critical path. Prefetch of plane k+1 issues right after the ds_write.
// Grid/dbuf (R22: 512 blocks, np=3-4, 53.8KB), v-scan, pool, bucket
// verbatim.

#define N_ 8
#define C_ 245
#define H_ 80
#define W_ 80
#define R_ 8192
#define P_ 7
#define SROW 84                    // row stride in floats (21 float4)

// XLA-style separately-rounded a*b + c in f32; barriers forbid contraction.
__device__ __forceinline__ float sep_ma(float a, float b, float c) {
    float p = a * b;                 // v_mul_f32, IEEE RN
    asm volatile("" : "+v"(p));      // contraction barrier
    float s = p + c;                 // v_add_f32, IEEE RN
    asm volatile("" : "+v"(s));
    return s;
}

// ---- kernel 1: bucket build, 512 thr, wave-scan (1 barrier) ----
__global__ __launch_bounds__(512) void bucket_kernel(
    const float* __restrict__ box, int* __restrict__ cnt,
    int* __restrict__ buckets)
{
    __shared__ int wtot[8];
    int b = blockIdx.x;                    // image
    int t = threadIdx.x;
    int r0 = t * 16;                       // contiguous range per thread

    unsigned match = 0u;
    int m = 0;
    #pragma unroll
    for (int k = 0; k < 16; ++k) {
        int bb = (int)box[(size_t)(r0 + k) * 5];
        if (bb == b) { match |= 1u << k; ++m; }
    }

    int lane = t & 63, wid = t >> 6;
    int incl = m;
    #pragma unroll
    for (int d = 1; d < 64; d <<= 1) {
        int v = __shfl_up(incl, d);
        if (lane >= d) incl += v;
    }
    if (lane == 63) wtot[wid] = incl;
    __syncthreads();
    int wpref = 0;
    #pragma unroll
    for (int w = 0; w < 8; ++w) wpref += (w < wid) ? wtot[w] : 0;
    int pos = wpref + incl - m;            // exclusive prefix

    #pragma unroll
    for (int k = 0; k < 16; ++k)
        if (match & (1u << k)) buckets[b * R_ + pos++] = r0 + k;
    if (t == 511) cnt[b] = wpref + incl;
}

__device__ __forceinline__ float4 f4_add(float4 a, float4 b) {
    return make_float4(a.x + b.x, a.y + b.y, a.z + b.z, a.w + b.w);
}

// ---- kernel 2: persistent 3-4-plane blocks, reg h-scan, dbuf LDS ----
__global__ __launch_bounds__(512) void fused_kernel(
    const float* __restrict__ fsam,
    const float* __restrict__ box,
    const int* __restrict__ cnt,
    const int* __restrict__ buckets,
    float* __restrict__ out)
{
    __shared__ float S[2][H_ * SROW];      // 2 x 26880 B = 53760 B
    int id  = blockIdx.x;                  // 0..511
    int b   = id & 7;                      // image (XCD swizzle: XCD = b)
    int s   = id >> 3;                     // 0..63
    int np  = (s < 53) ? 4 : 3;            // planes: c = s + 64k
    int tid = threadIdx.x;

    int n  = cnt[b];
    const int* lst = buckets + b * R_;

    // h-scan ownership: thread (row, q) owns cols q*20..q*20+19 of row
    int hrow = tid >> 2, hq = tid & 3;     // valid for tid < 320

    // register staging: 5 float4 = this thread's row-quarter
    float4 pf0, pf1, pf2, pf3, pf4;
    auto do_load = [&](int c) {
        if (tid < 320) {
            const float4* src = (const float4*)
                (fsam + ((size_t)b * C_ + c) * (H_ * W_) + hrow * W_ + hq * 20);
            pf0 = src[0]; pf1 = src[1]; pf2 = src[2]; pf3 = src[3]; pf4 = src[4];
        }
    };

    do_load(s);                            // prologue: plane 0

    for (int k = 0; k < np; ++k) {
        int c = s + 64 * k;
        float* B = S[k & 1];

        // ---- h-scan in registers + write scanned rows to LDS ----
        if (tid < 320) {
            float v[20];
            v[0]=pf0.x; v[1]=pf0.y; v[2]=pf0.z; v[3]=pf0.w;
            v[4]=pf1.x; v[5]=pf1.y; v[6]=pf1.z; v[7]=pf1.w;
            v[8]=pf2.x; v[9]=pf2.y; v[10]=pf2.z; v[11]=pf2.w;
            v[12]=pf3.x; v[13]=pf3.y; v[14]=pf3.z; v[15]=pf3.w;
            v[16]=pf4.x; v[17]=pf4.y; v[18]=pf4.z; v[19]=pf4.w;
            float run = 0.0f;
            #pragma unroll
            for (int j = 0; j < 20; ++j) { run += v[j]; v[j] = run; }
            float incl = run;
            #pragma unroll
            for (int d = 1; d < 4; d <<= 1) {
                float u = __shfl_up(incl, d, 4);
                if (hq >= d) incl += u;
            }
            float off = incl - run;
            #pragma unroll
            for (int j = 0; j < 20; ++j) v[j] += off;
            float4* base = (float4*)B + hrow * 21 + hq * 5;
            #pragma unroll
            for (int kk = 0; kk < 5; ++kk)
                base[kk] = make_float4(v[4*kk+0], v[4*kk+1], v[4*kk+2], v[4*kk+3]);
        }

        if (k + 1 < np) do_load(s + 64 * (k + 1));   // hides under v-scan+pool
        __syncthreads();                   // h-scanned plane ready in B

        // ---- vertical scan: 20 col-groups x 16 chunks of 5 rows ----
        if (tid < 320) {
            int cg = tid >> 4;             // 0..19
            int ch = tid & 15;             // 0..15
            float4* col = (float4*)B + cg;
            float4 v[5];
            float4 run = make_float4(0.f, 0.f, 0.f, 0.f);
            #pragma unroll
            for (int j = 0; j < 5; ++j) {
                run = f4_add(run, col[(ch * 5 + j) * 21]);
                v[j] = run;
            }
            float4 incl = run;
            #pragma unroll
            for (int d = 1; d < 16; d <<= 1) {
                float4 u;
                u.x = __shfl_up(incl.x, d, 16);
                u.y = __shfl_up(incl.y, d, 16);
                u.z = __shfl_up(incl.z, d, 16);
                u.w = __shfl_up(incl.w, d, 16);
                if (ch >= d) incl = f4_add(incl, u);
            }
            float4 off = make_float4(incl.x - run.x, incl.y - run.y,
                                     incl.z - run.z, incl.w - run.w);
            #pragma unroll
            for (int j = 0; j < 5; ++j)
                col[(ch * 5 + j) * 21] = f4_add(v[j], off);
        }
        __syncthreads();

        // ---- pool this image's ROIs from SAT in B ----
        int ph = (c / P_) % P_;            // block-uniform
        int pw = c % P_;

        for (int i = tid; i < n; i += 512) {
            int r = lst[i];
            const float* bx = box + (size_t)r * 5;

            // ---- R10-frozen edge arithmetic ----
            float x1 = rintf(bx[1]);
            float y1 = rintf(bx[2]);
            float x2 = rintf(bx[3] + 1.0f);
            float y2 = rintf(bx[4] + 1.0f);

            float roi_w = fmaxf(x2 - x1, 0.1f);
            float roi_h = fmaxf(y2 - y1, 0.1f);

            const float RCP7 = __uint_as_float(0x3E124925u); // fl32(1/7)
            float bin_w = roi_w * RCP7;
            float bin_h = roi_h * RCP7;
            asm volatile("" : "+v"(bin_w), "+v"(bin_h));

            float hs_f = floorf(sep_ma((float)ph,       bin_h, y1));
            float he_f = ceilf (sep_ma((float)(ph + 1), bin_h, y1));
            float ws_f = floorf(sep_ma((float)pw,       bin_w, x1));
            float we_f = ceilf (sep_ma((float)(pw + 1), bin_w, x1));

            int hs = (int)fminf(fmaxf(hs_f, 0.0f), 80.0f);
            int he = (int)fminf(fmaxf(he_f, 0.0f), 80.0f);
            int ws = (int)fminf(fmaxf(ws_f, 0.0f), 80.0f);
            int we = (int)fminf(fmaxf(we_f, 0.0f), 80.0f);

            // SAT taps with implicit zero row/col (clamp + select)
            int i1 = he > 0 ? he - 1 : 0, i0 = hs > 0 ? hs - 1 : 0;
            int j1 = we > 0 ? we - 1 : 0, j0 = ws > 0 ? ws - 1 : 0;
            float v11 = B[i1 * SROW + j1];
            float v01 = B[i0 * SROW + j1];
            float v10 = B[i1 * SROW + j0];
            float v00 = B[i0 * SROW + j0];
            float t11 = (he > 0 && we > 0) ? v11 : 0.0f;
            float t01 = (hs > 0 && we > 0) ? v01 : 0.0f;
            float t10 = (he > 0 && ws > 0) ? v10 : 0.0f;
            float t00 = (hs > 0 && ws > 0) ? v00 : 0.0f;
            float bin_sum = ((t11 - t01) - t10) + t00;   // ref op order

            int area = (he - hs) * (we - ws);
            out[(size_t)r * C_ + c] = (area > 0) ? bin_sum / (float)area : 0.0f;
        }
        // no barrier: next iteration writes S[(k+1)&1]; the last reader of
        // that buffer (pool of plane k-1) is 2 barriers upstream.
    }
}

// ---- fallback: R11 direct-sum kernel (ws too small) ----
__global__ __launch_bounds__(256) void psroi_direct_kernel(
    const float* __restrict__ fsam,
    const float* __restrict__ box,
    float* __restrict__ out)
{
    int id = blockIdx.x;
    int j  = id & 7;
    int m  = id >> 3;
    int g  = (m < 512) ? j : j + 8;
    int l  = (m < 512) ? m : m - 512;
    int c    = g * 16 + (l >> 5);
    int rblk = l & 31;
    if (c >= C_) return;

    int r = rblk * 256 + (int)threadIdx.x;
    int pw = c % P_;
    int ph = (c / P_) % P_;

    const float* bx = box + (size_t)r * 5;
    int   b  = (int)bx[0];
    float x1 = rintf(bx[1]);
    float y1 = rintf(bx[2]);
    float x2 = rintf(bx[3] + 1.0f);
    float y2 = rintf(bx[4] + 1.0f);

    float roi_w = fmaxf(x2 - x1, 0.1f);
    float roi_h = fmaxf(y2 - y1, 0.1f);

    const float RCP7 = __uint_as_float(0x3E124925u);
    float bin_w = roi_w * RCP7;
    float bin_h = roi_h * RCP7;
    asm volatile("" : "+v"(bin_w), "+v"(bin_h));

    float hs_f = floorf(sep_ma((float)ph,       bin_h, y1));
    float he_f = ceilf (sep_ma((float)(ph + 1), bin_h, y1));
    float ws_f = floorf(sep_ma((float)pw,       bin_w, x1));
    float we_f = ceilf (sep_ma((float)(pw + 1), bin_w, x1));

    int hs = (int)fminf(fmaxf(hs_f, 0.0f), 80.0f);
    int he = (int)fminf(fmaxf(he_f, 0.0f), 80.0f);
    int ws = (int)fminf(fmaxf(ws_f, 0.0f), 80.0f);
    int we = (int)fminf(fmaxf(we_f, 0.0f), 80.0f);

    const float* plane = fsam + ((size_t)b * C_ + c) * (H_ * W_);
    float s = 0.0f;
    for (int y = hs; y < he; ++y) {
        const float* row = plane + y * W_;
        for (int x = ws; x < we; ++x) s += row[x];
    }
    int area = (he - hs) * (we - ws);
    out[(size_t)r * C_ + c] = (area > 0) ? s / (float)area : 0.0f;
}

extern "C" void kernel_launch(void* const* d_in, const int* in_sizes, int n_in,
                              void* d_out, int out_size, void* d_ws, size_t ws_size,
                              hipStream_t stream) {
    const float* fsam = (const float*)d_in[0];
    const float* box  = (const float*)d_in[1];
    float* out = (float*)d_out;

    // ws layout: [0,32) counts (8 ints), [32, 32+8*8192*4) buckets
    size_t need = 32 + (size_t)N_ * R_ * sizeof(int);   // 262176 B
    if (ws_size >= need) {
        int* cnt     = (int*)d_ws;
        int* buckets = (int*)((char*)d_ws + 32);
        bucket_kernel<<<N_, 512, 0, stream>>>(box, cnt, buckets);
        fused_kernel<<<8 * 64, 512, 0, stream>>>(fsam, box, cnt, buckets, out);
    } else {
        psroi_direct_kernel<<<8192, 256, 0, stream>>>(fsam, box, out);
    }
}

// Round 25
// 33.558 us; speedup vs baseline: 1.0563x; 1.0563x over previous
//
#include <hip/hip_runtime.h>

// PSROI pooling: fsam (N=8, C=245, H=80, W=80) f32, box (R=8192, 5) f32
// out (R, 245) f32. out[r, c] = mean over fsam[b, c, hs:he, ws:we].
//
// ARITHMETIC (frozen since R10, DO NOT TOUCH): bin = roi * fl32(1/7)
// (reciprocal multiply, 0x3E124925) and edges = SEPARATELY-rounded
// g*bin + off (asm barriers). Matches ref (absmax <= 0.016 << 0.0725).
//
// R24: occupancy, tested cleanly. R20-R23 all ~35us with every pipe <50%
// and 2 resident blocks/CU (53.8KB dbuf) - phase latencies had only 2-way
// cross-block overlap. Now: 1960 single-plane blocks x 320 threads x ONE
// 26.9KB buffer + R23's reg h-scan (2 barriers/plane). Single plane per
// block -> no cross-plane LDS hazard -> no dbuf/extra barrier (R21's
// confound). 5 resident blocks/CU (134.4KB), 25 waves, 5-way phase
// stagger; 320 thr = exact scan task count (no idle waves in scans);
// fine-grained blocks smooth the tail. Scan/pool/edge code verbatim ->
// bit-identical output (absmax 0.015625).

#define N_ 8
#define C_ 245
#define H_ 80
#define W_ 80
#define R_ 8192
#define P_ 7
#define SROW 84                    // row stride in floats (21 float4)

// XLA-style separately-rounded a*b + c in f32; barriers forbid contraction.
__device__ __forceinline__ float sep_ma(float a, float b, float c) {
    float p = a * b;                 // v_mul_f32, IEEE RN
    asm volatile("" : "+v"(p));      // contraction barrier
    float s = p + c;                 // v_add_f32, IEEE RN
    asm volatile("" : "+v"(s));
    return s;
}

// ---- kernel 1: bucket build, 512 thr, wave-scan (1 barrier) ----
__global__ __launch_bounds__(512) void bucket_kernel(
    const float* __restrict__ box, int* __restrict__ cnt,
    int* __restrict__ buckets)
{
    __shared__ int wtot[8];
    int b = blockIdx.x;                    // image
    int t = threadIdx.x;
    int r0 = t * 16;                       // contiguous range per thread

    unsigned match = 0u;
    int m = 0;
    #pragma unroll
    for (int k = 0; k < 16; ++k) {
        int bb = (int)box[(size_t)(r0 + k) * 5];
        if (bb == b) { match |= 1u << k; ++m; }
    }

    int lane = t & 63, wid = t >> 6;
    int incl = m;
    #pragma unroll
    for (int d = 1; d < 64; d <<= 1) {
        int v = __shfl_up(incl, d);
        if (lane >= d) incl += v;
    }
    if (lane == 63) wtot[wid] = incl;
    __syncthreads();
    int wpref = 0;
    #pragma unroll
    for (int w = 0; w < 8; ++w) wpref += (w < wid) ? wtot[w] : 0;
    int pos = wpref + incl - m;            // exclusive prefix

    #pragma unroll
    for (int k = 0; k < 16; ++k)
        if (match & (1u << k)) buckets[b * R_ + pos++] = r0 + k;
    if (t == 511) cnt[b] = wpref + incl;
}

__device__ __forceinline__ float4 f4_add(float4 a, float4 b) {
    return make_float4(a.x + b.x, a.y + b.y, a.z + b.z, a.w + b.w);
}

// ---- kernel 2: one plane per block, 320 thr, reg h-scan, 1 buffer ----
__global__ __launch_bounds__(320) void fused_kernel(
    const float* __restrict__ fsam,
    const float* __restrict__ box,
    const int* __restrict__ cnt,
    const int* __restrict__ buckets,
    float* __restrict__ out)
{
    __shared__ float B[H_ * SROW];         // 26880 B
    int id  = blockIdx.x;                  // 0..1959
    int b   = id & 7;                      // image (XCD swizzle: XCD = b)
    int c   = id >> 3;                     // channel 0..244
    int tid = threadIdx.x;                 // 0..319

    int n  = cnt[b];
    const int* lst = buckets + b * R_;

    // h-scan ownership: thread (row, q) owns cols q*20..q*20+19 of row
    int hrow = tid >> 2, hq = tid & 3;

    // ---- load row-quarter straight into registers ----
    const float4* src = (const float4*)
        (fsam + ((size_t)b * C_ + c) * (H_ * W_) + hrow * W_ + hq * 20);
    float4 pf0 = src[0], pf1 = src[1], pf2 = src[2], pf3 = src[3], pf4 = src[4];

    // ---- h-scan in registers + write scanned rows to LDS ----
    {
        float v[20];
        v[0]=pf0.x; v[1]=pf0.y; v[2]=pf0.z; v[3]=pf0.w;
        v[4]=pf1.x; v[5]=pf1.y; v[6]=pf1.z; v[7]=pf1.w;
        v[8]=pf2.x; v[9]=pf2.y; v[10]=pf2.z; v[11]=pf2.w;
        v[12]=pf3.x; v[13]=pf3.y; v[14]=pf3.z; v[15]=pf3.w;
        v[16]=pf4.x; v[17]=pf4.y; v[18]=pf4.z; v[19]=pf4.w;
        float run = 0.0f;
        #pragma unroll
        for (int j = 0; j < 20; ++j) { run += v[j]; v[j] = run; }
        float incl = run;
        #pragma unroll
        for (int d = 1; d < 4; d <<= 1) {
            float u = __shfl_up(incl, d, 4);
            if (hq >= d) incl += u;
        }
        float off = incl - run;
        #pragma unroll
        for (int j = 0; j < 20; ++j) v[j] += off;
        float4* base = (float4*)B + hrow * 21 + hq * 5;
        #pragma unroll
        for (int kk = 0; kk < 5; ++kk)
            base[kk] = make_float4(v[4*kk+0], v[4*kk+1], v[4*kk+2], v[4*kk+3]);
    }
    __syncthreads();                       // h-scanned plane ready in B

    // ---- vertical scan: 20 col-groups x 16 chunks of 5 rows ----
    {
        int cg = tid >> 4;                 // 0..19
        int ch = tid & 15;                 // 0..15
        float4* col = (float4*)B + cg;
        float4 v[5];
        float4 run = make_float4(0.f, 0.f, 0.f, 0.f);
        #pragma unroll
        for (int j = 0; j < 5; ++j) {
            run = f4_add(run, col[(ch * 5 + j) * 21]);
            v[j] = run;
        }
        float4 incl = run;
        #pragma unroll
        for (int d = 1; d < 16; d <<= 1) {
            float4 u;
            u.x = __shfl_up(incl.x, d, 16);
            u.y = __shfl_up(incl.y, d, 16);
            u.z = __shfl_up(incl.z, d, 16);
            u.w = __shfl_up(incl.w, d, 16);
            if (ch >= d) incl = f4_add(incl, u);
        }
        float4 off = make_float4(incl.x - run.x, incl.y - run.y,
                                 incl.z - run.z, incl.w - run.w);
        #pragma unroll
        for (int j = 0; j < 5; ++j)
            col[(ch * 5 + j) * 21] = f4_add(v[j], off);
    }
    __syncthreads();

    // ---- pool this image's ROIs from SAT in B ----
    int ph = (c / P_) % P_;                // block-uniform
    int pw = c % P_;

    for (int i = tid; i < n; i += 320) {
        int r = lst[i];
        const float* bx = box + (size_t)r * 5;

        // ---- R10-frozen edge arithmetic ----
        float x1 = rintf(bx[1]);
        float y1 = rintf(bx[2]);
        float x2 = rintf(bx[3] + 1.0f);
        float y2 = rintf(bx[4] + 1.0f);

        float roi_w = fmaxf(x2 - x1, 0.1f);
        float roi_h = fmaxf(y2 - y1, 0.1f);

        const float RCP7 = __uint_as_float(0x3E124925u); // fl32(1/7)
        float bin_w = roi_w * RCP7;
        float bin_h = roi_h * RCP7;
        asm volatile("" : "+v"(bin_w), "+v"(bin_h));

        float hs_f = floorf(sep_ma((float)ph,       bin_h, y1));
        float he_f = ceilf (sep_ma((float)(ph + 1), bin_h, y1));
        float ws_f = floorf(sep_ma((float)pw,       bin_w, x1));
        float we_f = ceilf (sep_ma((float)(pw + 1), bin_w, x1));

        int hs = (int)fminf(fmaxf(hs_f, 0.0f), 80.0f);
        int he = (int)fminf(fmaxf(he_f, 0.0f), 80.0f);
        int ws = (int)fminf(fmaxf(ws_f, 0.0f), 80.0f);
        int we = (int)fminf(fmaxf(we_f, 0.0f), 80.0f);

        // SAT taps with implicit zero row/col (clamp + select)
        int i1 = he > 0 ? he - 1 : 0, i0 = hs > 0 ? hs - 1 : 0;
        int j1 = we > 0 ? we - 1 : 0, j0 = ws > 0 ? ws - 1 : 0;
        float v11 = B[i1 * SROW + j1];
        float v01 = B[i0 * SROW + j1];
        float v10 = B[i1 * SROW + j0];
        float v00 = B[i0 * SROW + j0];
        float t11 = (he > 0 && we > 0) ? v11 : 0.0f;
        float t01 = (hs > 0 && we > 0) ? v01 : 0.0f;
        float t10 = (he > 0 && ws > 0) ? v10 : 0.0f;
        float t00 = (hs > 0 && ws > 0) ? v00 : 0.0f;
        float bin_sum = ((t11 - t01) - t10) + t00;   // ref op order

        int area = (he - hs) * (we - ws);
        out[(size_t)r * C_ + c] = (area > 0) ? bin_sum / (float)area : 0.0f;
    }
}

// ---- fallback: R11 direct-sum kernel (ws too small) ----
__global__ __launch_bounds__(256) void psroi_direct_kernel(
    const float* __restrict__ fsam,
    const float* __restrict__ box,
    float* __restrict__ out)
{
    int id = blockIdx.x;
    int j  = id & 7;
    int m  = id >> 3;
    int g  = (m < 512) ? j : j + 8;
    int l  = (m < 512) ? m : m - 512;
    int c    = g * 16 + (l >> 5);
    int rblk = l & 31;
    if (c >= C_) return;

    int r = rblk * 256 + (int)threadIdx.x;
    int pw = c % P_;
    int ph = (c / P_) % P_;

    const float* bx = box + (size_t)r * 5;
    int   b  = (int)bx[0];
    float x1 = rintf(bx[1]);
    float y1 = rintf(bx[2]);
    float x2 = rintf(bx[3] + 1.0f);
    float y2 = rintf(bx[4] + 1.0f);

    float roi_w = fmaxf(x2 - x1, 0.1f);
    float roi_h = fmaxf(y2 - y1, 0.1f);

    const float RCP7 = __uint_as_float(0x3E124925u);
    float bin_w = roi_w * RCP7;
    float bin_h = roi_h * RCP7;
    asm volatile("" : "+v"(bin_w), "+v"(bin_h));

    float hs_f = floorf(sep_ma((float)ph,       bin_h, y1));
    float he_f = ceilf (sep_ma((float)(ph + 1), bin_h, y1));
    float ws_f = floorf(sep_ma((float)pw,       bin_w, x1));
    float we_f = ceilf (sep_ma((float)(pw + 1), bin_w, x1));

    int hs = (int)fminf(fmaxf(hs_f, 0.0f), 80.0f);
    int he = (int)fminf(fmaxf(he_f, 0.0f), 80.0f);
    int ws = (int)fminf(fmaxf(ws_f, 0.0f), 80.0f);
    int we = (int)fminf(fmaxf(we_f, 0.0f), 80.0f);

    const float* plane = fsam + ((size_t)b * C_ + c) * (H_ * W_);
    float s = 0.0f;
    for (int y = hs; y < he; ++y) {
        const float* row = plane + y * W_;
        for (int x = ws; x < we; ++x) s += row[x];
    }
    int area = (he - hs) * (we - ws);
    out[(size_t)r * C_ + c] = (area > 0) ? s / (float)area : 0.0f;
}

extern "C" void kernel_launch(void* const* d_in, const int* in_sizes, int n_in,
                              void* d_out, int out_size, void* d_ws, size_t ws_size,
                              hipStream_t stream) {
    const float* fsam = (const float*)d_in[0];
    const float* box  = (const float*)d_in[1];
    float* out = (float*)d_out;

    // ws layout: [0,32) counts (8 ints), [32, 32+8*8192*4) buckets
    size_t need = 32 + (size_t)N_ * R_ * sizeof(int);   // 262176 B
    if (ws_size >= need) {
        int* cnt     = (int*)d_ws;
        int* buckets = (int*)((char*)d_ws + 32);
        bucket_kernel<<<N_, 512, 0, stream>>>(box, cnt, buckets);
        fused_kernel<<<N_ * C_, 320, 0, stream>>>(fsam, box, cnt, buckets, out);
    } else {
        psroi_direct_kernel<<<8192, 256, 0, stream>>>(fsam, box, out);
    }
}

// Round 26
// 33.392 us; speedup vs baseline: 1.0615x; 1.0050x over previous
//
#include <hip/hip_runtime.h>

// PSROI pooling: fsam (N=8, C=245, H=80, W=80) f32, box (R=8192, 5) f32
// out (R, 245) f32. out[r, c] = mean over fsam[b, c, hs:he, ws:we].
//
// ARITHMETIC (frozen since R10, DO NOT TOUCH): bin = roi * fl32(1/7)
// (reciprocal multiply, 0x3E124925) and edges = SEPARATELY-rounded
// g*bin + off (asm barriers). Matches ref (absmax <= 0.016 << 0.0725).
//
// R24: occupancy, tested cleanly. R20-R23 all ~35us with every pipe <50%
// and 2 resident blocks/CU (53.8KB dbuf) - phase latencies had only 2-way
// cross-block overlap. Now: 1960 single-plane blocks x 320 threads x ONE
// 26.9KB buffer + R23's reg h-scan (2 barriers/plane). Single plane per
// block -> no cross-plane LDS hazard -> no dbuf/extra barrier (R21's
// confound). 5 resident blocks/CU (134.4KB), 25 waves, 5-way phase
// stagger; 320 thr = exact scan task count (no idle waves in scans);
// fine-grained blocks smooth the tail. Scan/pool/edge code verbatim ->
// bit-identical output (absmax 0.015625).

#define N_ 8
#define C_ 245
#define H_ 80
#define W_ 80
#define R_ 8192
#define P_ 7
#define SROW 84                    // row stride in floats (21 float4)

// XLA-style separately-rounded a*b + c in f32; barriers forbid contraction.
__device__ __forceinline__ float sep_ma(float a, float b, float c) {
    float p = a * b;                 // v_mul_f32, IEEE RN
    asm volatile("" : "+v"(p));      // contraction barrier
    float s = p + c;                 // v_add_f32, IEEE RN
    asm volatile("" : "+v"(s));
    return s;
}

// ---- kernel 1: bucket build, 512 thr, wave-scan (1 barrier) ----
__global__ __launch_bounds__(512) void bucket_kernel(
    const float* __restrict__ box, int* __restrict__ cnt,
    int* __restrict__ buckets)
{
    __shared__ int wtot[8];
    int b = blockIdx.x;                    // image
    int t = threadIdx.x;
    int r0 = t * 16;                       // contiguous range per thread

    unsigned match = 0u;
    int m = 0;
    #pragma unroll
    for (int k = 0; k < 16; ++k) {
        int bb = (int)box[(size_t)(r0 + k) * 5];
        if (bb == b) { match |= 1u << k; ++m; }
    }

    int lane = t & 63, wid = t >> 6;
    int incl = m;
    #pragma unroll
    for (int d = 1; d < 64; d <<= 1) {
        int v = __shfl_up(incl, d);
        if (lane >= d) incl += v;
    }
    if (lane == 63) wtot[wid] = incl;
    __syncthreads();
    int wpref = 0;
    #pragma unroll
    for (int w = 0; w < 8; ++w) wpref += (w < wid) ? wtot[w] : 0;
    int pos = wpref + incl - m;            // exclusive prefix

    #pragma unroll
    for (int k = 0; k < 16; ++k)
        if (match & (1u << k)) buckets[b * R_ + pos++] = r0 + k;
    if (t == 511) cnt[b] = wpref + incl;
}

__device__ __forceinline__ float4 f4_add(float4 a, float4 b) {
    return make_float4(a.x + b.x, a.y + b.y, a.z + b.z, a.w + b.w);
}

// ---- kernel 2: one plane per block, 320 thr, reg h-scan, 1 buffer ----
__global__ __launch_bounds__(320) void fused_kernel(
    const float* __restrict__ fsam,
    const float* __restrict__ box,
    const int* __restrict__ cnt,
    const int* __restrict__ buckets,
    float* __restrict__ out)
{
    __shared__ float B[H_ * SROW];         // 26880 B
    int id  = blockIdx.x;                  // 0..1959
    int b   = id & 7;                      // image (XCD swizzle: XCD = b)
    int c   = id >> 3;                     // channel 0..244
    int tid = threadIdx.x;                 // 0..319

    int n  = cnt[b];
    const int* lst = buckets + b * R_;

    // h-scan ownership: thread (row, q) owns cols q*20..q*20+19 of row
    int hrow = tid >> 2, hq = tid & 3;

    // ---- load row-quarter straight into registers ----
    const float4* src = (const float4*)
        (fsam + ((size_t)b * C_ + c) * (H_ * W_) + hrow * W_ + hq * 20);
    float4 pf0 = src[0], pf1 = src[1], pf2 = src[2], pf3 = src[3], pf4 = src[4];

    // ---- h-scan in registers + write scanned rows to LDS ----
    {
        float v[20];
        v[0]=pf0.x; v[1]=pf0.y; v[2]=pf0.z; v[3]=pf0.w;
        v[4]=pf1.x; v[5]=pf1.y; v[6]=pf1.z; v[7]=pf1.w;
        v[8]=pf2.x; v[9]=pf2.y; v[10]=pf2.z; v[11]=pf2.w;
        v[12]=pf3.x; v[13]=pf3.y; v[14]=pf3.z; v[15]=pf3.w;
        v[16]=pf4.x; v[17]=pf4.y; v[18]=pf4.z; v[19]=pf4.w;
        float run = 0.0f;
        #pragma unroll
        for (int j = 0; j < 20; ++j) { run += v[j]; v[j] = run; }
        float incl = run;
        #pragma unroll
        for (int d = 1; d < 4; d <<= 1) {
            float u = __shfl_up(incl, d, 4);
            if (hq >= d) incl += u;
        }
        float off = incl - run;
        #pragma unroll
        for (int j = 0; j < 20; ++j) v[j] += off;
        float4* base = (float4*)B + hrow * 21 + hq * 5;
        #pragma unroll
        for (int kk = 0; kk < 5; ++kk)
            base[kk] = make_float4(v[4*kk+0], v[4*kk+1], v[4*kk+2], v[4*kk+3]);
    }
    __syncthreads();                       // h-scanned plane ready in B

    // ---- vertical scan: 20 col-groups x 16 chunks of 5 rows ----
    {
        int cg = tid >> 4;                 // 0..19
        int ch = tid & 15;                 // 0..15
        float4* col = (float4*)B + cg;
        float4 v[5];
        float4 run = make_float4(0.f, 0.f, 0.f, 0.f);
        #pragma unroll
        for (int j = 0; j < 5; ++j) {
            run = f4_add(run, col[(ch * 5 + j) * 21]);
            v[j] = run;
        }
        float4 incl = run;
        #pragma unroll
        for (int d = 1; d < 16; d <<= 1) {
            float4 u;
            u.x = __shfl_up(incl.x, d, 16);
            u.y = __shfl_up(incl.y, d, 16);
            u.z = __shfl_up(incl.z, d, 16);
            u.w = __shfl_up(incl.w, d, 16);
            if (ch >= d) incl = f4_add(incl, u);
        }
        float4 off = make_float4(incl.x - run.x, incl.y - run.y,
                                 incl.z - run.z, incl.w - run.w);
        #pragma unroll
        for (int j = 0; j < 5; ++j)
            col[(ch * 5 + j) * 21] = f4_add(v[j], off);
    }
    __syncthreads();

    // ---- pool this image's ROIs from SAT in B ----
    int ph = (c / P_) % P_;                // block-uniform
    int pw = c % P_;

    for (int i = tid; i < n; i += 320) {
        int r = lst[i];
        const float* bx = box + (size_t)r * 5;

        // ---- R10-frozen edge arithmetic ----
        float x1 = rintf(bx[1]);
        float y1 = rintf(bx[2]);
        float x2 = rintf(bx[3] + 1.0f);
        float y2 = rintf(bx[4] + 1.0f);

        float roi_w = fmaxf(x2 - x1, 0.1f);
        float roi_h = fmaxf(y2 - y1, 0.1f);

        const float RCP7 = __uint_as_float(0x3E124925u); // fl32(1/7)
        float bin_w = roi_w * RCP7;
        float bin_h = roi_h * RCP7;
        asm volatile("" : "+v"(bin_w), "+v"(bin_h));

        float hs_f = floorf(sep_ma((float)ph,       bin_h, y1));
        float he_f = ceilf (sep_ma((float)(ph + 1), bin_h, y1));
        float ws_f = floorf(sep_ma((float)pw,       bin_w, x1));
        float we_f = ceilf (sep_ma((float)(pw + 1), bin_w, x1));

        int hs = (int)fminf(fmaxf(hs_f, 0.0f), 80.0f);
        int he = (int)fminf(fmaxf(he_f, 0.0f), 80.0f);
        int ws = (int)fminf(fmaxf(ws_f, 0.0f), 80.0f);
        int we = (int)fminf(fmaxf(we_f, 0.0f), 80.0f);

        // SAT taps with implicit zero row/col (clamp + select)
        int i1 = he > 0 ? he - 1 : 0, i0 = hs > 0 ? hs - 1 : 0;
        int j1 = we > 0 ? we - 1 : 0, j0 = ws > 0 ? ws - 1 : 0;
        float v11 = B[i1 * SROW + j1];
        float v01 = B[i0 * SROW + j1];
        float v10 = B[i1 * SROW + j0];
        float v00 = B[i0 * SROW + j0];
        float t11 = (he > 0 && we > 0) ? v11 : 0.0f;
        float t01 = (hs > 0 && we > 0) ? v01 : 0.0f;
        float t10 = (he > 0 && ws > 0) ? v10 : 0.0f;
        float t00 = (hs > 0 && ws > 0) ? v00 : 0.0f;
        float bin_sum = ((t11 - t01) - t10) + t00;   // ref op order

        int area = (he - hs) * (we - ws);
        out[(size_t)r * C_ + c] = (area > 0) ? bin_sum / (float)area : 0.0f;
    }
}

// ---- fallback: R11 direct-sum kernel (ws too small) ----
__global__ __launch_bounds__(256) void psroi_direct_kernel(
    const float* __restrict__ fsam,
    const float* __restrict__ box,
    float* __restrict__ out)
{
    int id = blockIdx.x;
    int j  = id & 7;
    int m  = id >> 3;
    int g  = (m < 512) ? j : j + 8;
    int l  = (m < 512) ? m : m - 512;
    int c    = g * 16 + (l >> 5);
    int rblk = l & 31;
    if (c >= C_) return;

    int r = rblk * 256 + (int)threadIdx.x;
    int pw = c % P_;
    int ph = (c / P_) % P_;

    const float* bx = box + (size_t)r * 5;
    int   b  = (int)bx[0];
    float x1 = rintf(bx[1]);
    float y1 = rintf(bx[2]);
    float x2 = rintf(bx[3] + 1.0f);
    float y2 = rintf(bx[4] + 1.0f);

    float roi_w = fmaxf(x2 - x1, 0.1f);
    float roi_h = fmaxf(y2 - y1, 0.1f);

    const float RCP7 = __uint_as_float(0x3E124925u);
    float bin_w = roi_w * RCP7;
    float bin_h = roi_h * RCP7;
    asm volatile("" : "+v"(bin_w), "+v"(bin_h));

    float hs_f = floorf(sep_ma((float)ph,       bin_h, y1));
    float he_f = ceilf (sep_ma((float)(ph + 1), bin_h, y1));
    float ws_f = floorf(sep_ma((float)pw,       bin_w, x1));
    float we_f = ceilf (sep_ma((float)(pw + 1), bin_w, x1));

    int hs = (int)fminf(fmaxf(hs_f, 0.0f), 80.0f);
    int he = (int)fminf(fmaxf(he_f, 0.0f), 80.0f);
    int ws = (int)fminf(fmaxf(ws_f, 0.0f), 80.0f);
    int we = (int)fminf(fmaxf(we_f, 0.0f), 80.0f);

    const float* plane = fsam + ((size_t)b * C_ + c) * (H_ * W_);
    float s = 0.0f;
    for (int y = hs; y < he; ++y) {
        const float* row = plane + y * W_;
        for (int x = ws; x < we; ++x) s += row[x];
    }
    int area = (he - hs) * (we - ws);
    out[(size_t)r * C_ + c] = (area > 0) ? s / (float)area : 0.0f;
}

extern "C" void kernel_launch(void* const* d_in, const int* in_sizes, int n_in,
                              void* d_out, int out_size, void* d_ws, size_t ws_size,
                              hipStream_t stream) {
    const float* fsam = (const float*)d_in[0];
    const float* box  = (const float*)d_in[1];
    float* out = (float*)d_out;

    // ws layout: [0,32) counts (8 ints), [32, 32+8*8192*4) buckets
    size_t need = 32 + (size_t)N_ * R_ * sizeof(int);   // 262176 B
    if (ws_size >= need) {
        int* cnt     = (int*)d_ws;
        int* buckets = (int*)((char*)d_ws + 32);
        bucket_kernel<<<N_, 512, 0, stream>>>(box, cnt, buckets);
        fused_kernel<<<N_ * C_, 320, 0, stream>>>(fsam, box, cnt, buckets, out);
    } else {
        psroi_direct_kernel<<<8192, 256, 0, stream>>>(fsam, box, out);
    }
}